// Round 4
// baseline (123.418 us; speedup 1.0000x reference)
//
#include <hip/hip_runtime.h>

#define WW 512
#define HH 256
#define TS 48
#define NB 2
#define ZT 4                 // z-rows per block (= waves per block)
#define NZT (HH / ZT)        // 64
#define THALF (TS / 2)       // 24
#define KAPPA 0.01f
#define NU 0.01f

#define ROW(zz) (min(max((zz), 0), HH - 1) * WW)
#define LD4(p) (*reinterpret_cast<const float4*>(p))
#define LD2(p) (*reinterpret_cast<const float2*>(p))

__device__ __forceinline__ float elem(const float4 v, int e) {
    return e == 0 ? v.x : e == 1 ? v.y : e == 2 ? v.z : v.w;
}
__device__ __forceinline__ float4 f4add(const float4 a, const float4 b) {
    return make_float4(a.x + b.x, a.y + b.y, a.z + b.z, a.w + b.w);
}

// jnp.gradient first+second (gradient-of-gradient) along one axis, index i of n.
__device__ __forceinline__ void grad12(float fm2, float fm1, float fc, float fp1, float fp2,
                                       int i, int n, float invh, float& g, float& gg) {
    const float half = 0.5f * invh;
    if (i == 0) {
        g = (fp1 - fc) * invh;
        float g1 = (fp2 - fc) * half;
        gg = (g1 - g) * invh;
    } else if (i == n - 1) {
        g = (fc - fm1) * invh;
        float gm = (fc - fm2) * half;
        gg = (g - gm) * invh;
    } else {
        g = (fp1 - fm1) * half;
        float gim = (i == 1)     ? (fc - fm1) * invh : (fc - fm2) * half;
        float gip = (i == n - 2) ? (fp1 - fc) * invh : (fp2 - fc) * half;
        gg = (gip - gim) * half;
    }
}

__device__ __forceinline__ float grad1(float fm1, float fc, float fp1, int i, int n, float invh) {
    if (i == 0)     return (fp1 - fc) * invh;
    if (i == n - 1) return (fc - fm1) * invh;
    return (fp1 - fm1) * (0.5f * invh);
}

__global__ __launch_bounds__(256, 2) void rbc_loss_kernel(const float* __restrict__ pred,
                                                          double* __restrict__ dacc) {
    const int sT = HH * WW;          // 131072
    const int sC = TS * sT;          // 6291456
    const int sB = 5 * sC;

    // XCD-chunked swizzle: 512 blocks, 64 per XCD -> one XCD covers all zt of
    // one (b, th, xh): contiguous z working set stays in its L2.
    const int bi = blockIdx.x;
    const int n  = (bi & 7) * (gridDim.x >> 3) + (bi >> 3);

    const int zt = n & (NZT - 1);      // logical n = ((b*2+th)*2+xh)*64 + zt
    const int xh = (n >> 6) & 1;
    const int th = (n >> 7) & 1;
    const int b  = n >> 8;

    const int lane = threadIdx.x & 63, w = threadIdx.x >> 6;
    const int z  = zt * ZT + w;              // uniform per wave
    const int x0 = (xh << 8) + (lane << 2);  // quad base
    const int t0 = th * THALF;

    const float invdt = TS / 10.0f;
    const float invdx = (float)(WW / 6.283185307179586);
    const float invdz = HH / 2.0f;

    const float* __restrict__ pT = pred + (size_t)b * sB + 0 * (size_t)sC;
    const float* __restrict__ pU = pred + (size_t)b * sB + 1 * (size_t)sC;
    const float* __restrict__ pV = pred + (size_t)b * sB + 2 * (size_t)sC;
    const float* __restrict__ q3 = pred + (size_t)b * sB + 3 * (size_t)sC;
    const float* __restrict__ q4 = pred + (size_t)b * sB + 4 * (size_t)sC;

    const int rC   = z * WW + x0;
    const int rzm2 = ROW(z - 2) + x0, rzm1 = ROW(z - 1) + x0;
    const int rzp1 = ROW(z + 1) + x0, rzp2 = ROW(z + 2) + x0;

    const bool isR = (xh == 0) && (lane == 63);   // needs x=256,257
    const bool isL = (xh == 1) && (lane == 0);    // needs x=254,255
    const int rSeam  = z * WW + (isR ? 256 : 254);
    const int rSeamP = z * WW + (isR ? 256 : 255);

    // t-ring warm-up: centers at t0-1 (clamped; unused when t0==0) and t0
    const int tp0 = max(t0 - 1, 0);
    float4 Tp = LD4(pT + (size_t)tp0 * sT + rC);
    float4 Up = LD4(pU + (size_t)tp0 * sT + rC);
    float4 Vp = LD4(pV + (size_t)tp0 * sT + rC);
    float4 Tc = LD4(pT + (size_t)t0 * sT + rC);
    float4 Uc = LD4(pU + (size_t)t0 * sT + rC);
    float4 Vc = LD4(pV + (size_t)t0 * sT + rC);

    // double-buffered T/u/w z-stencil rows
    float4 Tm2A, Tm1A, Tp1A, Tp2A, Um2A, Um1A, Up1A, Up2A, Vm2A, Vm1A, Vp1A, Vp2A;
    float4 Tm2B, Tm1B, Tp1B, Tp2B, Um2B, Um1B, Up1B, Up2B, Vm2B, Vm1B, Vp1B, Vp2B;

#define LOADI(S, tcur) do {                                                       \
    const size_t _o = (size_t)(tcur) * sT;                                        \
    Tm2##S = LD4(pT + _o + rzm2); Tm1##S = LD4(pT + _o + rzm1);                   \
    Tp1##S = LD4(pT + _o + rzp1); Tp2##S = LD4(pT + _o + rzp2);                   \
    Um2##S = LD4(pU + _o + rzm2); Um1##S = LD4(pU + _o + rzm1);                   \
    Up1##S = LD4(pU + _o + rzp1); Up2##S = LD4(pU + _o + rzp2);                   \
    Vm2##S = LD4(pV + _o + rzm2); Vm1##S = LD4(pV + _o + rzm1);                   \
    Vp1##S = LD4(pV + _o + rzp1); Vp2##S = LD4(pV + _o + rzp2);                   \
} while (0)

#define COMPUTE(S, tcur) do {                                                     \
    const int _tn = min((tcur) + 1, TS - 1);                                      \
    float4 Tn = LD4(pT + (size_t)_tn * sT + rC);                                  \
    float4 Un = LD4(pU + (size_t)_tn * sT + rC);                                  \
    float4 Vn = LD4(pV + (size_t)_tn * sT + rC);                                  \
    const size_t _oc = (size_t)(tcur) * sT;                                       \
    float4 A3m = LD4(q3 + _oc + rzm1), A3c = LD4(q3 + _oc + rC), A3p = LD4(q3 + _oc + rzp1); \
    float4 A4m = LD4(q4 + _oc + rzm1), A4c = LD4(q4 + _oc + rC), A4p = LD4(q4 + _oc + rzp1); \
    float2 Tse = make_float2(0.f, 0.f), Use = Tse, Vse = Tse; float Pse = 0.f;    \
    if (isR | isL) {                                                              \
        Tse = LD2(pT + _oc + rSeam); Use = LD2(pU + _oc + rSeam);                 \
        Vse = LD2(pV + _oc + rSeam);                                              \
        Pse = q3[_oc + rSeamP] + q4[_oc + rSeamP];                                \
    }                                                                             \
    float Tl2 = __shfl_up(Tc.z, 1),   Tl3 = __shfl_up(Tc.w, 1);                   \
    float Tr0 = __shfl_down(Tc.x, 1), Tr1 = __shfl_down(Tc.y, 1);                 \
    float Ul2 = __shfl_up(Uc.z, 1),   Ul3 = __shfl_up(Uc.w, 1);                   \
    float Ur0 = __shfl_down(Uc.x, 1), Ur1 = __shfl_down(Uc.y, 1);                 \
    float Vl2 = __shfl_up(Vc.z, 1),   Vl3 = __shfl_up(Vc.w, 1);                   \
    float Vr0 = __shfl_down(Vc.x, 1), Vr1 = __shfl_down(Vc.y, 1);                 \
    float4 Pc = f4add(A3c, A4c), Pm1 = f4add(A3m, A4m), Pp1 = f4add(A3p, A4p);    \
    float Pl3 = __shfl_up(Pc.w, 1),   Pr0 = __shfl_down(Pc.x, 1);                 \
    if (isR) { Tr0 = Tse.x; Tr1 = Tse.y; Ur0 = Use.x; Ur1 = Use.y;                \
               Vr0 = Vse.x; Vr1 = Vse.y; Pr0 = Pse; }                             \
    if (isL) { Tl2 = Tse.x; Tl3 = Tse.y; Ul2 = Use.x; Ul3 = Use.y;                \
               Vl2 = Vse.x; Vl3 = Vse.y; Pl3 = Pse; }                             \
    _Pragma("unroll")                                                             \
    for (int e = 0; e < 4; ++e) {                                                 \
        const int i = x0 + e;                                                     \
        const float txm2 = e == 0 ? Tl2 : e == 1 ? Tl3 : elem(Tc, e - 2);         \
        const float txm1 = e == 0 ? Tl3 : elem(Tc, e - 1);                        \
        const float txc  = elem(Tc, e);                                           \
        const float txp1 = e == 3 ? Tr0 : elem(Tc, e + 1);                        \
        const float txp2 = e == 2 ? Tr0 : e == 3 ? Tr1 : elem(Tc, e + 2);         \
        const float uxm2 = e == 0 ? Ul2 : e == 1 ? Ul3 : elem(Uc, e - 2);         \
        const float uxm1 = e == 0 ? Ul3 : elem(Uc, e - 1);                        \
        const float uxc  = elem(Uc, e);                                           \
        const float uxp1 = e == 3 ? Ur0 : elem(Uc, e + 1);                        \
        const float uxp2 = e == 2 ? Ur0 : e == 3 ? Ur1 : elem(Uc, e + 2);         \
        const float vxm2 = e == 0 ? Vl2 : e == 1 ? Vl3 : elem(Vc, e - 2);         \
        const float vxm1 = e == 0 ? Vl3 : elem(Vc, e - 1);                        \
        const float vxc  = elem(Vc, e);                                           \
        const float vxp1 = e == 3 ? Vr0 : elem(Vc, e + 1);                        \
        const float vxp2 = e == 2 ? Vr0 : e == 3 ? Vr1 : elem(Vc, e + 2);         \
        const float pxm1 = e == 0 ? Pl3 : elem(Pc, e - 1);                        \
        const float pxc  = elem(Pc, e);                                           \
        const float pxp1 = e == 3 ? Pr0 : elem(Pc, e + 1);                        \
        float dTdx, dTdxx, dTdz, dTdzz;                                           \
        grad12(txm2, txm1, txc, txp1, txp2, i, WW, invdx, dTdx, dTdxx);           \
        grad12(elem(Tm2##S, e), elem(Tm1##S, e), txc, elem(Tp1##S, e), elem(Tp2##S, e), z, HH, invdz, dTdz, dTdzz); \
        float dUdx, dUdxx, dUdz, dUdzz;                                           \
        grad12(uxm2, uxm1, uxc, uxp1, uxp2, i, WW, invdx, dUdx, dUdxx);           \
        grad12(elem(Um2##S, e), elem(Um1##S, e), uxc, elem(Up1##S, e), elem(Up2##S, e), z, HH, invdz, dUdz, dUdzz); \
        float dVdx, dVdxx, dVdz, dVdzz;                                           \
        grad12(vxm2, vxm1, vxc, vxp1, vxp2, i, WW, invdx, dVdx, dVdxx);           \
        grad12(elem(Vm2##S, e), elem(Vm1##S, e), vxc, elem(Vp1##S, e), elem(Vp2##S, e), z, HH, invdz, dVdz, dVdzz); \
        float dPdx = grad1(pxm1, pxc, pxp1, i, WW, invdx);                        \
        float dPdz = grad1(elem(Pm1, e), pxc, elem(Pp1, e), z, HH, invdz);        \
        float dTdt, dUdt, dVdt;                                                   \
        if ((tcur) == 0) {                                                        \
            dTdt = (elem(Tn, e) - txc) * invdt;                                   \
            dUdt = (elem(Un, e) - uxc) * invdt;                                   \
            dVdt = (elem(Vn, e) - vxc) * invdt;                                   \
        } else if ((tcur) == TS - 1) {                                            \
            dTdt = (txc - elem(Tp, e)) * invdt;                                   \
            dUdt = (uxc - elem(Up, e)) * invdt;                                   \
            dVdt = (vxc - elem(Vp, e)) * invdt;                                   \
        } else {                                                                  \
            dTdt = (elem(Tn, e) - elem(Tp, e)) * (0.5f * invdt);                  \
            dUdt = (elem(Un, e) - elem(Up, e)) * (0.5f * invdt);                  \
            dVdt = (elem(Vn, e) - elem(Vp, e)) * (0.5f * invdt);                  \
        }                                                                         \
        float dv = dUdx + dVdz;                                                   \
        float te = dTdt + uxc * dTdx + vxc * dTdz - KAPPA * (dTdxx + dTdzz);      \
        float xm = dUdt + uxc * dUdx + vxc * dUdz + dPdx - NU * (dUdxx + dUdzz);  \
        float zm = dVdt + uxc * dVdx + vxc * dVdz + dPdz - NU * (dVdxx + dVdzz) - txc; \
        acc += dv * dv + te * te + xm * xm + zm * zm;                             \
    }                                                                             \
    Tp = Tc; Tc = Tn; Up = Uc; Uc = Un; Vp = Vc; Vc = Vn;                         \
} while (0)

    float acc = 0.f;

    LOADI(A, t0);
    #pragma unroll 1
    for (int tt = t0; tt < t0 + THALF; tt += 2) {
        LOADI(B, tt + 1);         // prefetch next t's stencil while computing
        COMPUTE(A, tt);
        if (tt + 2 < t0 + THALF) { LOADI(A, tt + 2); }
        COMPUTE(B, tt + 1);
    }

    // block reduction: wave shfl -> LDS -> one double atomic per block
    #pragma unroll
    for (int off = 32; off; off >>= 1) acc += __shfl_down(acc, off, 64);
    __shared__ float wsum[4];
    if (lane == 0) wsum[w] = acc;
    __syncthreads();
    if (threadIdx.x == 0) {
        atomicAdd(dacc, (double)(wsum[0] + wsum[1] + wsum[2] + wsum[3]));
    }
}

__global__ void rbc_finalize(const double* __restrict__ dacc, float* __restrict__ out) {
    const double N = (double)NB * TS * HH * WW;   // 12,582,912
    out[0] = (float)(dacc[0] / N);
}

extern "C" void kernel_launch(void* const* d_in, const int* in_sizes, int n_in,
                              void* d_out, int out_size, void* d_ws, size_t ws_size,
                              hipStream_t stream) {
    const float* pred = (const float*)d_in[0];
    double* dacc = (double*)d_ws;
    hipMemsetAsync(dacc, 0, sizeof(double), stream);

    const int nblocks = NB * 2 * 2 * NZT;   // 512 blocks x 256 threads
    rbc_loss_kernel<<<nblocks, 256, 0, stream>>>(pred, dacc);
    rbc_finalize<<<1, 1, 0, stream>>>(dacc, (float*)d_out);
}

// Round 5
// 101.230 us; speedup vs baseline: 1.2192x; 1.2192x over previous
//
#include <hip/hip_runtime.h>

#define WW 512
#define HH 256
#define TS 48
#define NB 2
#define TCH 12               // t-steps per block
#define NCH (TS / TCH)       // 4 chunks
#define KAPPA 0.01f
#define NU 0.01f

#define ROW(zz) (min(max((zz), 0), HH - 1) * WW)
#define LD2(p) (*reinterpret_cast<const float2*>(p))

__device__ __forceinline__ float2 f2add(const float2 a, const float2 b) {
    return make_float2(a.x + b.x, a.y + b.y);
}

// jnp.gradient first+second (gradient-of-gradient) along one axis, index i of n.
__device__ __forceinline__ void grad12(float fm2, float fm1, float fc, float fp1, float fp2,
                                       int i, int n, float invh, float& g, float& gg) {
    const float half = 0.5f * invh;
    if (i == 0) {
        g = (fp1 - fc) * invh;
        float g1 = (fp2 - fc) * half;
        gg = (g1 - g) * invh;
    } else if (i == n - 1) {
        g = (fc - fm1) * invh;
        float gm = (fc - fm2) * half;
        gg = (g - gm) * invh;
    } else {
        g = (fp1 - fm1) * half;
        float gim = (i == 1)     ? (fc - fm1) * invh : (fc - fm2) * half;
        float gip = (i == n - 2) ? (fp1 - fc) * invh : (fp2 - fc) * half;
        gg = (gip - gim) * half;
    }
}

__device__ __forceinline__ float grad1(float fm1, float fc, float fp1, int i, int n, float invh) {
    if (i == 0)     return (fp1 - fc) * invh;
    if (i == n - 1) return (fc - fm1) * invh;
    return (fp1 - fm1) * (0.5f * invh);
}

__global__ __launch_bounds__(256, 4) void rbc_loss_kernel(const float* __restrict__ pred,
                                                          double* __restrict__ dacc) {
    const int sT = HH * WW;          // 131072
    const int sC = TS * sT;
    const int sB = 5 * sC;

    // XCD-chunked swizzle: 2048 blocks, 256 per XCD -> one XCD sweeps all z of
    // one (b, tc): z-neighbor row sharing stays inside its L2.
    const int bi = blockIdx.x;
    const int n  = (bi & 7) * (gridDim.x >> 3) + (bi >> 3);

    const int z  = n & (HH - 1);          // logical n = ((b*NCH + tc)*HH + z)
    const int tc = (n >> 8) & (NCH - 1);
    const int b  = n >> 10;
    const int t0 = tc * TCH;

    const int lane = threadIdx.x & 63, w = threadIdx.x >> 6;
    const int x0 = threadIdx.x << 1;      // pair base, 0..510

    const float invdt = TS / 10.0f;
    const float invdx = (float)(WW / 6.283185307179586);
    const float invdz = HH / 2.0f;

    const float* __restrict__ pT = pred + (size_t)b * sB + 0 * (size_t)sC;
    const float* __restrict__ pU = pred + (size_t)b * sB + 1 * (size_t)sC;
    const float* __restrict__ pV = pred + (size_t)b * sB + 2 * (size_t)sC;
    const float* __restrict__ q3 = pred + (size_t)b * sB + 3 * (size_t)sC;
    const float* __restrict__ q4 = pred + (size_t)b * sB + 4 * (size_t)sC;

    const int rC   = z * WW + x0;
    const int rzm2 = ROW(z - 2) + x0, rzm1 = ROW(z - 1) + x0;
    const int rzp1 = ROW(z + 1) + x0, rzp2 = ROW(z + 2) + x0;

    const bool needL = (lane == 0)  && (x0 != 0);    // wave seam, not grid edge
    const bool needR = (lane == 63) && (x0 != 510);
    const int sL = z * WW + x0 - 2;   // covers x0-2, x0-1
    const int sR = z * WW + x0 + 2;   // covers x0+2, x0+3

    // t-ring warm-up (t0-1 clamped; only used by central/backward branches)
    const int tp0 = max(t0 - 1, 0);
    float2 Tp = LD2(pT + (size_t)tp0 * sT + rC);
    float2 Up = LD2(pU + (size_t)tp0 * sT + rC);
    float2 Vp = LD2(pV + (size_t)tp0 * sT + rC);
    float2 Tc = LD2(pT + (size_t)t0 * sT + rC);
    float2 Uc = LD2(pU + (size_t)t0 * sT + rC);
    float2 Vc = LD2(pV + (size_t)t0 * sT + rC);

    float acc = 0.f;

    #pragma unroll 1
    for (int t = t0; t < t0 + TCH; ++t) {
        const size_t o  = (size_t)t * sT;
        const size_t on = (size_t)min(t + 1, TS - 1) * sT;

        // t+1 centers (first HBM touch of plane t+1) + P rows first
        float2 Tn = LD2(pT + on + rC);
        float2 Un = LD2(pU + on + rC);
        float2 Vn = LD2(pV + on + rC);
        float2 Pm1 = f2add(LD2(q3 + o + rzm1), LD2(q4 + o + rzm1));
        float2 Pc  = f2add(LD2(q3 + o + rC),   LD2(q4 + o + rC));
        float2 Pp1 = f2add(LD2(q3 + o + rzp1), LD2(q4 + o + rzp1));
        // z-stencil rows (warm: fetched as centers by z-neighbor blocks)
        float2 Tm2 = LD2(pT + o + rzm2), Tm1 = LD2(pT + o + rzm1);
        float2 Tp1 = LD2(pT + o + rzp1), Tp2 = LD2(pT + o + rzp2);
        float2 Um2 = LD2(pU + o + rzm2), Um1 = LD2(pU + o + rzm1);
        float2 Up1 = LD2(pU + o + rzp1), Up2 = LD2(pU + o + rzp2);
        float2 Vm2 = LD2(pV + o + rzm2), Vm1 = LD2(pV + o + rzm1);
        float2 Vp1 = LD2(pV + o + rzp1), Vp2 = LD2(pV + o + rzp2);

        // x-neighbors from the ring via intra-wave shuffles
        float TLx = __shfl_up(Tc.x, 1), TLy = __shfl_up(Tc.y, 1);
        float TRx = __shfl_down(Tc.x, 1), TRy = __shfl_down(Tc.y, 1);
        float ULx = __shfl_up(Uc.x, 1), ULy = __shfl_up(Uc.y, 1);
        float URx = __shfl_down(Uc.x, 1), URy = __shfl_down(Uc.y, 1);
        float VLx = __shfl_up(Vc.x, 1), VLy = __shfl_up(Vc.y, 1);
        float VRx = __shfl_down(Vc.x, 1), VRy = __shfl_down(Vc.y, 1);
        float PLy = __shfl_up(Pc.y, 1), PRx = __shfl_down(Pc.x, 1);

        if (needL) {   // lane 0 of a wave: pull x0-2, x0-1 (L1-hot)
            float2 s;
            s = LD2(pT + o + sL); TLx = s.x; TLy = s.y;
            s = LD2(pU + o + sL); ULx = s.x; ULy = s.y;
            s = LD2(pV + o + sL); VLx = s.x; VLy = s.y;
            PLy = q3[o + sL + 1] + q4[o + sL + 1];
        }
        if (needR) {   // lane 63 of a wave: pull x0+2, x0+3
            float2 s;
            s = LD2(pT + o + sR); TRx = s.x; TRy = s.y;
            s = LD2(pU + o + sR); URx = s.x; URy = s.y;
            s = LD2(pV + o + sR); VRx = s.x; VRy = s.y;
            PRx = q3[o + sR] + q4[o + sR];
        }

        #pragma unroll
        for (int e = 0; e < 2; ++e) {
            const int i = x0 + e;
            // x-stencil operand selection (e==0 / e==1)
            const float txm2 = e ? TLy : TLx, txm1 = e ? Tc.x : TLy;
            const float txc  = e ? Tc.y : Tc.x;
            const float txp1 = e ? TRx : Tc.y, txp2 = e ? TRy : TRx;
            const float uxm2 = e ? ULy : ULx, uxm1 = e ? Uc.x : ULy;
            const float uxc  = e ? Uc.y : Uc.x;
            const float uxp1 = e ? URx : Uc.y, uxp2 = e ? URy : URx;
            const float vxm2 = e ? VLy : VLx, vxm1 = e ? Vc.x : VLy;
            const float vxc  = e ? Vc.y : Vc.x;
            const float vxp1 = e ? VRx : Vc.y, vxp2 = e ? VRy : VRx;
            const float pxm1 = e ? Pc.x : PLy;
            const float pxc  = e ? Pc.y : Pc.x;
            const float pxp1 = e ? PRx : Pc.y;
            // z-stencil / t-ring element
            const float tzm2 = e ? Tm2.y : Tm2.x, tzm1 = e ? Tm1.y : Tm1.x;
            const float tzp1 = e ? Tp1.y : Tp1.x, tzp2 = e ? Tp2.y : Tp2.x;
            const float uzm2 = e ? Um2.y : Um2.x, uzm1 = e ? Um1.y : Um1.x;
            const float uzp1 = e ? Up1.y : Up1.x, uzp2 = e ? Up2.y : Up2.x;
            const float vzm2 = e ? Vm2.y : Vm2.x, vzm1 = e ? Vm1.y : Vm1.x;
            const float vzp1 = e ? Vp1.y : Vp1.x, vzp2 = e ? Vp2.y : Vp2.x;
            const float pzm1 = e ? Pm1.y : Pm1.x, pzp1 = e ? Pp1.y : Pp1.x;
            const float tpv = e ? Tp.y : Tp.x, tnv = e ? Tn.y : Tn.x;
            const float upv = e ? Up.y : Up.x, unv = e ? Un.y : Un.x;
            const float vpv = e ? Vp.y : Vp.x, vnv = e ? Vn.y : Vn.x;

            float dTdx, dTdxx, dTdz, dTdzz;
            grad12(txm2, txm1, txc, txp1, txp2, i, WW, invdx, dTdx, dTdxx);
            grad12(tzm2, tzm1, txc, tzp1, tzp2, z, HH, invdz, dTdz, dTdzz);
            float dUdx, dUdxx, dUdz, dUdzz;
            grad12(uxm2, uxm1, uxc, uxp1, uxp2, i, WW, invdx, dUdx, dUdxx);
            grad12(uzm2, uzm1, uxc, uzp1, uzp2, z, HH, invdz, dUdz, dUdzz);
            float dVdx, dVdxx, dVdz, dVdzz;
            grad12(vxm2, vxm1, vxc, vxp1, vxp2, i, WW, invdx, dVdx, dVdxx);
            grad12(vzm2, vzm1, vxc, vzp1, vzp2, z, HH, invdz, dVdz, dVdzz);

            float dPdx = grad1(pxm1, pxc, pxp1, i, WW, invdx);
            float dPdz = grad1(pzm1, pxc, pzp1, z, HH, invdz);

            float dTdt, dUdt, dVdt;   // t is loop-uniform
            if (t == 0) {
                dTdt = (tnv - txc) * invdt;
                dUdt = (unv - uxc) * invdt;
                dVdt = (vnv - vxc) * invdt;
            } else if (t == TS - 1) {
                dTdt = (txc - tpv) * invdt;
                dUdt = (uxc - upv) * invdt;
                dVdt = (vxc - vpv) * invdt;
            } else {
                dTdt = (tnv - tpv) * (0.5f * invdt);
                dUdt = (unv - upv) * (0.5f * invdt);
                dVdt = (vnv - vpv) * (0.5f * invdt);
            }

            float dv = dUdx + dVdz;
            float te = dTdt + uxc * dTdx + vxc * dTdz - KAPPA * (dTdxx + dTdzz);
            float xm = dUdt + uxc * dUdx + vxc * dUdz + dPdx - NU * (dUdxx + dUdzz);
            float zm = dVdt + uxc * dVdx + vxc * dVdz + dPdz - NU * (dVdxx + dVdzz) - txc;

            acc += dv * dv + te * te + xm * xm + zm * zm;
        }

        Tp = Tc; Tc = Tn;
        Up = Uc; Uc = Un;
        Vp = Vc; Vc = Vn;
    }

    // block reduction: wave shfl -> LDS -> one double atomic per block
    #pragma unroll
    for (int off = 32; off; off >>= 1) acc += __shfl_down(acc, off, 64);
    __shared__ float wsum[4];
    if (lane == 0) wsum[w] = acc;
    __syncthreads();
    if (threadIdx.x == 0) {
        atomicAdd(dacc, (double)(wsum[0] + wsum[1] + wsum[2] + wsum[3]));
    }
}

__global__ void rbc_finalize(const double* __restrict__ dacc, float* __restrict__ out) {
    const double N = (double)NB * TS * HH * WW;   // 12,582,912
    out[0] = (float)(dacc[0] / N);
}

extern "C" void kernel_launch(void* const* d_in, const int* in_sizes, int n_in,
                              void* d_out, int out_size, void* d_ws, size_t ws_size,
                              hipStream_t stream) {
    const float* pred = (const float*)d_in[0];
    double* dacc = (double*)d_ws;
    hipMemsetAsync(dacc, 0, sizeof(double), stream);

    const int nblocks = NB * NCH * HH;   // 2048 blocks x 256 threads
    rbc_loss_kernel<<<nblocks, 256, 0, stream>>>(pred, dacc);
    rbc_finalize<<<1, 1, 0, stream>>>(dacc, (float*)d_out);
}